// Round 1
// baseline (181.268 us; speedup 1.0000x reference)
//
#include <hip/hip_runtime.h>

typedef __attribute__((ext_vector_type(4))) float f32x4;
typedef __attribute__((ext_vector_type(8))) short s16x8;

__device__ inline unsigned short f2bf(float f) {
  unsigned int u = __builtin_bit_cast(unsigned int, f);
  u += 0x7fff + ((u >> 16) & 1);   // RTNE
  return (unsigned short)(u >> 16);
}

// ---------------- K0: cast / transpose ----------------
__global__ __launch_bounds__(256) void cast_kernel(
    const float* __restrict__ v, const float* __restrict__ k, const float* __restrict__ q,
    const float* __restrict__ wq, const float* __restrict__ wk, const float* __restrict__ wv,
    const float* __restrict__ wo, const float* __restrict__ pos,
    unsigned short* __restrict__ qbf, unsigned short* __restrict__ kbf,
    unsigned short* __restrict__ vbf, unsigned short* __restrict__ wqT,
    unsigned short* __restrict__ wkT, unsigned short* __restrict__ wvT,
    unsigned short* __restrict__ woT, unsigned short* __restrict__ ebf) {
  int seg = blockIdx.y;
  int tid = blockIdx.x * blockDim.x + threadIdx.x;
  int stride = gridDim.x * blockDim.x;
  if (seg < 3) {
    const float* src = seg == 0 ? q : (seg == 1 ? k : v);
    unsigned short* dst = seg == 0 ? qbf : (seg == 1 ? kbf : vbf);
    for (int i = tid; i < 4096 * 512; i += stride) dst[i] = f2bf(src[i]);
  } else if (seg < 7) {
    const float* src = seg == 3 ? wq : seg == 4 ? wk : seg == 5 ? wv : wo;
    unsigned short* dst = seg == 3 ? wqT : seg == 4 ? wkT : seg == 5 ? wvT : woT;
    for (int i = tid; i < 512 * 512; i += stride) {
      int kk = i >> 9, n = i & 511;
      dst[n * 512 + kk] = f2bf(src[i]);  // transpose: Wt[n][k] = W[k][n]
    }
  } else {
    for (int i = tid; i < 1024 * 64; i += stride) ebf[i] = f2bf(pos[1024 * 64 + i]);
  }
}

// ---------------- K1/K3: 128x128 bf16 GEMM, K=512 ----------------
// A: [M][512] bf16 row-major. Bt: [512][512] bf16, row = output col (pre-transposed).
// MODE 0: bf16 out at [(n*8+h)][l][d]   (qh/kh)
// MODE 1: bf16 out at [(n*8+h)][d][l]   (vh transposed)
// MODE 2: fp32 out at [row][col]        (final out)
template <int MODE>
__global__ __launch_bounds__(256, 2) void gemm_kernel(
    const unsigned short* __restrict__ A, const unsigned short* __restrict__ Bt,
    const float* __restrict__ bias, void* __restrict__ outp) {
  __shared__ unsigned short As[128 * 32];
  __shared__ unsigned short Bs[128 * 32];
  int r0 = blockIdx.x * 128, c0 = blockIdx.y * 128;
  int tid = threadIdx.x;
  int lane = tid & 63, w = tid >> 6;
  int wr = w >> 1, wc = w & 1;
  int frow = lane & 15, kg = lane >> 4;
  f32x4 acc[4][4] = {};
  for (int k0 = 0; k0 < 512; k0 += 32) {
#pragma unroll
    for (int j = 0; j < 2; ++j) {
      int t = tid + j * 256;           // 0..511
      int row = t >> 2, col = (t & 3) * 8;
      *(s16x8*)&As[row * 32 + col] = *(const s16x8*)&A[(size_t)(r0 + row) * 512 + k0 + col];
      *(s16x8*)&Bs[row * 32 + col] = *(const s16x8*)&Bt[(size_t)(c0 + row) * 512 + k0 + col];
    }
    __syncthreads();
    s16x8 af[4], bf[4];
#pragma unroll
    for (int mi = 0; mi < 4; ++mi) af[mi] = *(s16x8*)&As[(wr * 64 + mi * 16 + frow) * 32 + kg * 8];
#pragma unroll
    for (int ni = 0; ni < 4; ++ni) bf[ni] = *(s16x8*)&Bs[(wc * 64 + ni * 16 + frow) * 32 + kg * 8];
#pragma unroll
    for (int mi = 0; mi < 4; ++mi)
#pragma unroll
      for (int ni = 0; ni < 4; ++ni)
        acc[mi][ni] = __builtin_amdgcn_mfma_f32_16x16x32_bf16(af[mi], bf[ni], acc[mi][ni], 0, 0, 0);
    __syncthreads();
  }
#pragma unroll
  for (int ni = 0; ni < 4; ++ni) {
    int gc = c0 + wc * 64 + ni * 16 + frow;
    float bi = bias[gc];
#pragma unroll
    for (int mi = 0; mi < 4; ++mi) {
#pragma unroll
      for (int reg = 0; reg < 4; ++reg) {
        int gr = r0 + wr * 64 + mi * 16 + kg * 4 + reg;
        float val = acc[mi][ni][reg] + bi;
        if (MODE == 0) {
          ((unsigned short*)outp)[(size_t)((gr >> 10) * 8 + (gc >> 6)) * 65536 +
                                  (size_t)(gr & 1023) * 64 + (gc & 63)] = f2bf(val);
        } else if (MODE == 1) {
          ((unsigned short*)outp)[(size_t)((gr >> 10) * 8 + (gc >> 6)) * 65536 +
                                  (size_t)(gc & 63) * 1024 + (gr & 1023)] = f2bf(val);
        } else {
          ((float*)outp)[(size_t)gr * 512 + gc] = val;
        }
      }
    }
  }
}

// ---------------- K2: fused relative attention ----------------
// Per block: one (nh), 16 query rows. 256 threads (4 waves).
// S: [16][1024] fp32, XOR-swizzled (byte ^= (row&7)<<4) to kill bank conflicts.
__global__ __launch_bounds__(256, 2) void attn_kernel(
    const unsigned short* __restrict__ qh, const unsigned short* __restrict__ kh,
    const unsigned short* __restrict__ vhT, const unsigned short* __restrict__ ebf,
    const float* __restrict__ mask, float* __restrict__ attn_out,
    unsigned short* __restrict__ ctx) {
  __shared__ float S[16 * 1024];
  __shared__ float rowsum[16];
  int nh = blockIdx.y;
  int l0 = blockIdx.x * 16;
  int tid = threadIdx.x;
  int lane = tid & 63, w = tid >> 6;
  int frow = lane & 15, kg = lane >> 4;

  auto sptr = [&](int r, int c) -> float* {
    int byte = (r << 12) + (c << 2);
    byte ^= (r & 7) << 4;
    return (float*)((char*)S + byte);
  };
  auto sptr4 = [&](int r, int c) -> f32x4* {  // c multiple of 4
    int byte = (r << 12) + (c << 2);
    byte ^= (r & 7) << 4;
    return (f32x4*)((char*)S + byte);
  };

  // Q fragments (row = frow, k = 32*half + kg*8 + j), direct from L2-hot global
  s16x8 qf0, qf1;
  {
    const unsigned short* qbase = qh + ((size_t)nh * 1024 + l0 + frow) * 64 + kg * 8;
    qf0 = *(const s16x8*)(qbase);
    qf1 = *(const s16x8*)(qbase + 32);
  }

  // ---- Phase A: QE = Qh @ E^T  (full 16x1024 into S) ----
  for (int t = 0; t < 16; ++t) {
    int j0 = w * 256 + t * 16;
    const unsigned short* eb = ebf + ((size_t)(j0 + frow)) * 64 + kg * 8;
    s16x8 b0 = *(const s16x8*)(eb);
    s16x8 b1 = *(const s16x8*)(eb + 32);
    f32x4 a = {};
    a = __builtin_amdgcn_mfma_f32_16x16x32_bf16(qf0, b0, a, 0, 0, 0);
    a = __builtin_amdgcn_mfma_f32_16x16x32_bf16(qf1, b1, a, 0, 0, 0);
#pragma unroll
    for (int reg = 0; reg < 4; ++reg) *sptr(kg * 4 + reg, j0 + frow) = a[reg];
  }
  __syncthreads();

  // ---- Phase B: QK^T, skew-gather srel from S, +mask, *scale ----
  f32x4 lg[16];
  for (int t = 0; t < 16; ++t) {
    int m0 = w * 256 + t * 16;
    const unsigned short* kb = kh + ((size_t)nh * 1024 + m0 + frow) * 64 + kg * 8;
    s16x8 b0 = *(const s16x8*)(kb);
    s16x8 b1 = *(const s16x8*)(kb + 32);
    f32x4 a = {};
    a = __builtin_amdgcn_mfma_f32_16x16x32_bf16(qf0, b0, a, 0, 0, 0);
    a = __builtin_amdgcn_mfma_f32_16x16x32_bf16(qf1, b1, a, 0, 0, 0);
    lg[t] = a;
  }
  for (int t = 0; t < 16; ++t) {
    int m = w * 256 + t * 16 + frow;
#pragma unroll
    for (int reg = 0; reg < 4; ++reg) {
      int r = kg * 4 + reg;
      int lq = l0 + r;
      float srel = (m <= lq) ? *sptr(r, 1023 + m - lq) : 0.f;
      lg[t][reg] = (lg[t][reg] + srel) * 0.125f + mask[(size_t)lq * 1024 + m] * -1e9f;
    }
  }
  __syncthreads();  // all srel reads done before logits overwrite S
  for (int t = 0; t < 16; ++t) {
    int m = w * 256 + t * 16 + frow;
#pragma unroll
    for (int reg = 0; reg < 4; ++reg) *sptr(kg * 4 + reg, m) = lg[t][reg];
  }
  __syncthreads();

  // ---- Phase C: softmax over rows; write normalized attn, keep raw exp in S ----
  {
    int r = tid >> 4, q16 = tid & 15;
    f32x4 va[16];
    float mx = -1e30f;
#pragma unroll
    for (int i = 0; i < 16; ++i) {
      va[i] = *sptr4(r, q16 * 4 + i * 64);
      mx = fmaxf(mx, fmaxf(fmaxf(va[i][0], va[i][1]), fmaxf(va[i][2], va[i][3])));
    }
#pragma unroll
    for (int d = 1; d < 16; d <<= 1) mx = fmaxf(mx, __shfl_xor(mx, d));
    float sum = 0.f;
#pragma unroll
    for (int i = 0; i < 16; ++i) {
      f32x4 p;
#pragma unroll
      for (int j = 0; j < 4; ++j) {
        p[j] = __expf(va[i][j] - mx);
        sum += p[j];
      }
      va[i] = p;
    }
#pragma unroll
    for (int d = 1; d < 16; d <<= 1) sum += __shfl_xor(sum, d);
    float inv = 1.f / sum;
    if (q16 == 0) rowsum[r] = sum;
    size_t abase = ((size_t)nh * 1024 + l0 + r) * 1024;
#pragma unroll
    for (int i = 0; i < 16; ++i) {
      int c = q16 * 4 + i * 64;
      *sptr4(r, c) = va[i];                     // raw exp for PV
      f32x4 outv = va[i] * inv;                 // normalized for output
      *(f32x4*)&attn_out[abase + c] = outv;
    }
  }
  __syncthreads();

  // ---- Phase D: ctx = P @ V  (unnormalized P, divide by rowsum at end) ----
  {
    int d0 = w * 16;
    const unsigned short* vb = vhT + ((size_t)nh * 64 + d0 + frow) * 1024;
    f32x4 acc = {};
    for (int ks = 0; ks < 32; ++ks) {
      int kk = ks * 32 + kg * 8;
      f32x4 f0 = *sptr4(frow, kk);
      f32x4 f1 = *sptr4(frow, kk + 4);
      s16x8 a;
#pragma unroll
      for (int j = 0; j < 4; ++j) {
        a[j] = (short)f2bf(f0[j]);
        a[j + 4] = (short)f2bf(f1[j]);
      }
      s16x8 b = *(const s16x8*)(vb + kk);
      acc = __builtin_amdgcn_mfma_f32_16x16x32_bf16(a, b, acc, 0, 0, 0);
    }
    int n = nh >> 3, h = nh & 7;
#pragma unroll
    for (int reg = 0; reg < 4; ++reg) {
      int rr = kg * 4 + reg;
      float val = acc[reg] / rowsum[rr];
      ctx[((size_t)(n * 1024 + l0 + rr)) * 512 + h * 64 + d0 + frow] = f2bf(val);
    }
  }
}

extern "C" void kernel_launch(void* const* d_in, const int* in_sizes, int n_in,
                              void* d_out, int out_size, void* d_ws, size_t ws_size,
                              hipStream_t stream) {
  const float* v = (const float*)d_in[0];
  const float* k = (const float*)d_in[1];
  const float* q = (const float*)d_in[2];
  const float* mask = (const float*)d_in[3];
  const float* wq_w = (const float*)d_in[4];
  const float* wq_b = (const float*)d_in[5];
  const float* wk_w = (const float*)d_in[6];
  const float* wk_b = (const float*)d_in[7];
  const float* wv_w = (const float*)d_in[8];
  const float* wv_b = (const float*)d_in[9];
  const float* wo_w = (const float*)d_in[10];
  const float* wo_b = (const float*)d_in[11];
  const float* pos = (const float*)d_in[12];

  float* outp = (float*)d_out;
  float* attn_out = outp + (size_t)4 * 1024 * 512;

  char* ws = (char*)d_ws;
  unsigned short* qbf = (unsigned short*)(ws);                              // 4 MB (reused as ctx)
  unsigned short* kbf = (unsigned short*)(ws + ((size_t)4 << 20));          // 4 MB
  unsigned short* vbf = (unsigned short*)(ws + ((size_t)8 << 20));          // 4 MB
  unsigned short* wqT = (unsigned short*)(ws + ((size_t)12 << 20));         // 512 KB
  unsigned short* wkT = (unsigned short*)(ws + ((size_t)12 << 20) + (512 << 10));
  unsigned short* wvT = (unsigned short*)(ws + ((size_t)13 << 20));
  unsigned short* woT = (unsigned short*)(ws + ((size_t)13 << 20) + (512 << 10));
  unsigned short* ebf = (unsigned short*)(ws + ((size_t)14 << 20));         // 128 KB
  unsigned short* qhw = (unsigned short*)(ws + ((size_t)16 << 20));         // 4 MB
  unsigned short* khw = (unsigned short*)(ws + ((size_t)20 << 20));         // 4 MB
  unsigned short* vhT = (unsigned short*)(ws + ((size_t)24 << 20));         // 4 MB
  unsigned short* ctx = qbf;  // qbf dead after first GEMM; attn runs later

  cast_kernel<<<dim3(1024, 8), 256, 0, stream>>>(v, k, q, wq_w, wk_w, wv_w, wo_w, pos,
                                                 qbf, kbf, vbf, wqT, wkT, wvT, woT, ebf);
  gemm_kernel<0><<<dim3(32, 4), 256, 0, stream>>>(qbf, wqT, wq_b, qhw);
  gemm_kernel<0><<<dim3(32, 4), 256, 0, stream>>>(kbf, wkT, wk_b, khw);
  gemm_kernel<1><<<dim3(32, 4), 256, 0, stream>>>(vbf, wvT, wv_b, vhT);
  attn_kernel<<<dim3(64, 32), 256, 0, stream>>>(qhw, khw, vhT, ebf, mask, attn_out, ctx);
  gemm_kernel<2><<<dim3(32, 4), 256, 0, stream>>>(ctx, woT, wo_b, outp);
}